// Round 9
// baseline (249.586 us; speedup 1.0000x reference)
//
#include <hip/hip_runtime.h>
#include <math.h>

#define T_TOK 2048
#define H_DIM 1024
#define I_DIM 512
#define N_EXP 16
#define TOPK  4
#define NPAIR (T_TOK*TOPK)   /* 8192 */

typedef unsigned short u16;
typedef __attribute__((ext_vector_type(8))) short s8v;   // 8 bf16 codes (4 VGPR)
typedef __attribute__((ext_vector_type(4))) float f4v;   // MFMA accumulator

#define GLDS(g, l) __builtin_amdgcn_global_load_lds( \
    (const __attribute__((address_space(1))) void*)(g), \
    (__attribute__((address_space(3))) void*)(l), 16, 0, 0)

// ---------- fp8 e4m3fn round-trip (RNE); input must be in [-448,448] ----------
__device__ __forceinline__ float fp8_rt(float v) {
    float av = fabsf(v);
    if (av < 0.015625f) {                 // subnormal region: quantum 2^-9
        return rintf(v * 512.0f) * 0.001953125f;
    }
    unsigned u = __float_as_uint(v);
    unsigned lsb = (u >> 20) & 1u;        // keep 3 mantissa bits, RNE
    u = (u + 0x7FFFFu + lsb) & 0xFFF00000u;
    return __uint_as_float(u);
}

__device__ __forceinline__ unsigned f2bf(float v) {  // exact for fp8-representable values
    return __float_as_uint(v) >> 16;
}

// ---------- K0: prep = weight cvt (f32 -> bf16 codes) + x quant + routing ----------
// blocks [0, 24576): cvt both weight tensors. One float4 per thread (16 B/lane
// contiguous load — the coalescing sweet spot), one int2 store (8 B/lane contiguous).
// blocks [24576, 26624): token t: quant x row t; threads 0-3 route the 4 slots.
#define NF4_GU (N_EXP * 2 * I_DIM * H_DIM / 4)   /* 4194304 float4 slots */
__global__ void k_prep(const float* __restrict__ wgu, u16* __restrict__ wgu_bf,
                       const float* __restrict__ wdn, u16* __restrict__ wdn_bf,
                       const float* __restrict__ x, u16* __restrict__ xq,
                       float* __restrict__ xs, const int* __restrict__ tki,
                       int* __restrict__ counts, int* __restrict__ lists) {
    int bid = blockIdx.x, tid = threadIdx.x;
    if (bid < 24576) {
        int i = bid * 256 + tid;                 // float4 slot
        const float* in = wgu; u16* out = wgu_bf;
        if (i >= NF4_GU) { in = wdn; out = wdn_bf; i -= NF4_GU; }
        float4 a = ((const float4*)in)[i];
        int2 st;
        st.x = (int)(f2bf(a.x) | (f2bf(a.y) << 16));
        st.y = (int)(f2bf(a.z) | (f2bf(a.w) << 16));
        ((int2*)out)[i] = st;
    } else {
        int t = bid - 24576;
        if (tid < 4) {                           // routing for token t's 4 slots
            int p = t * 4 + tid;
            int e = tki[p];
            int pos = atomicAdd(&counts[e], 1);
            lists[e * NPAIR + pos] = p;
        }
        float4 v = ((const float4*)(x + (size_t)t * H_DIM))[tid];
        float a = fmaxf(fmaxf(fabsf(v.x), fabsf(v.y)), fmaxf(fabsf(v.z), fabsf(v.w)));
        #pragma unroll
        for (int m = 16; m >= 1; m >>= 1) a = fmaxf(a, __shfl_xor(a, m));
        float s = fmaxf(a, 1e-10f) / 448.0f;
        ushort4 r;
        r.x = (u16)f2bf(fp8_rt(fminf(fmaxf(v.x / s, -448.f), 448.f)));
        r.y = (u16)f2bf(fp8_rt(fminf(fmaxf(v.y / s, -448.f), 448.f)));
        r.z = (u16)f2bf(fp8_rt(fminf(fmaxf(v.z / s, -448.f), 448.f)));
        r.w = (u16)f2bf(fp8_rt(fminf(fmaxf(v.w / s, -448.f), 448.f)));
        ((ushort4*)(xq + (size_t)t * H_DIM))[tid] = r;
        if ((tid & 31) == 0) xs[t * 8 + (tid >> 5)] = s;
    }
}

// ---------- K3: gate_up MFMA GEMM (R3-proven: 64x128 tile, dbuf, 1 sync/chunk) ----------
// grid 2048 1-D: e = bid&15 (XCD pin), tile = bid>>4: tt = tile>>3 (M-tile of 64 pairs),
// it = tile&7 (64 gate cols [it*64,+64) + 64 up cols [512+it*64,+64)).
// 256 thr = 4 waves (m = w&1 row-half, q = w>>1: 0=gate cols, 1=up cols), wave-tile 32x64.
// K=1024, BK=64 (16 chunks), fold scales every 2 chunks (kb = t>>1).
__global__ __launch_bounds__(256, 3)
void k_gateup(const u16* __restrict__ xq, const float* __restrict__ xs,
              const int* __restrict__ counts, const int* __restrict__ lists,
              const u16* __restrict__ wgu, const float* __restrict__ sgu,
              const u16* __restrict__ zbuf, float* __restrict__ hbuf) {
    int bid = blockIdx.x;
    int e = bid & 15, tile = bid >> 4;
    int tt = tile >> 3, it = tile & 7;
    int n = counts[e];
    if (tt * 64 >= n) return;

    __shared__ __align__(16) u16 sm[2][12288];   // per buf: B 1024 slots | A 512 slots (24 KB)
    __shared__ float xs_l[64][8];
    __shared__ int ptok[64];

    int tid = threadIdx.x;
    int w = tid >> 6, lane = tid & 63;
    int m = w & 1, q = w >> 1;
    int l15 = lane & 15, l4 = lane >> 4;

    if (tid < 64) {
        int slot = tt * 64 + tid;
        ptok[tid] = (slot < n) ? lists[e * NPAIR + slot] : -1;
    }
    __syncthreads();
    {
        int r = tid >> 2, kb4 = (tid & 3) * 2;
        int p = ptok[r];
        xs_l[r][kb4]     = (p >= 0) ? xs[(p >> 2) * 8 + kb4]     : 0.f;
        xs_l[r][kb4 + 1] = (p >= 0) ? xs[(p >> 2) * 8 + kb4 + 1] : 0.f;
    }

    // stage-source precompute (pre-swizzled global addresses; LDS dest stays linear)
    const u16* wbase = wgu + (size_t)e * 1024 * 1024;
    const u16* srcB[4];
    #pragma unroll
    for (int j = 0; j < 4; ++j) {
        int s = j * 256 + tid;
        int row = s >> 3, c = s & 7, cg = c ^ (row & 7);
        int nrow = (row < 64) ? it * 64 + row : 448 + it * 64 + row;  // gate | up
        srcB[j] = wbase + (size_t)nrow * H_DIM + cg * 8;
    }
    const u16* srcA[2];
    #pragma unroll
    for (int j = 0; j < 2; ++j) {
        int s = j * 256 + tid;
        int row = s >> 3, c = s & 7, cg = c ^ (row & 7);
        int p = ptok[row];
        srcA[j] = (p >= 0) ? xq + (size_t)(p >> 2) * H_DIM + cg * 8 : zbuf;
    }

    // fragment LDS read offsets (u16 units; row stride 64 u16 = 128B, XOR swizzle)
    int idxA[2][2], idxB[4][2];
    #pragma unroll
    for (int fm = 0; fm < 2; ++fm) {
        int ar = m * 32 + fm * 16 + l15;
        #pragma unroll
        for (int kg = 0; kg < 2; ++kg)
            idxA[fm][kg] = 8192 + ar * 64 + (((kg * 4 + l4) ^ (ar & 7)) * 8);
    }
    #pragma unroll
    for (int nf = 0; nf < 4; ++nf) {
        int br = q * 64 + nf * 16 + l15;
        #pragma unroll
        for (int kg = 0; kg < 2; ++kg)
            idxB[nf][kg] = br * 64 + (((kg * 4 + l4) ^ (br & 7)) * 8);
    }

    auto stage = [&](int buf) {
        #pragma unroll
        for (int j = 0; j < 4; ++j) { GLDS(srcB[j], &sm[buf][j * 2048 + tid * 8]); srcB[j] += 64; }
        #pragma unroll
        for (int j = 0; j < 2; ++j) { GLDS(srcA[j], &sm[buf][8192 + j * 2048 + tid * 8]); srcA[j] += 64; }
    };

    f4v master[2][4], part[2][4];
    #pragma unroll
    for (int a = 0; a < 2; ++a)
        #pragma unroll
        for (int b = 0; b < 4; ++b) { master[a][b] = (f4v){0,0,0,0}; part[a][b] = (f4v){0,0,0,0}; }

    const float* swp = sgu + e * 64 + (q ? 4 + (it >> 1) : (it >> 1)) * 8;

    stage(0);
    __syncthreads();

    for (int t = 0; t < 16; ++t) {
        if (t < 15) stage((t + 1) & 1);
        const u16* buf = &sm[t & 1][0];
        #pragma unroll
        for (int kg = 0; kg < 2; ++kg) {
            s8v a0 = *(const s8v*)&buf[idxA[0][kg]];
            s8v a1 = *(const s8v*)&buf[idxA[1][kg]];
            #pragma unroll
            for (int nf = 0; nf < 4; ++nf) {
                s8v b = *(const s8v*)&buf[idxB[nf][kg]];
                part[0][nf] = __builtin_amdgcn_mfma_f32_16x16x32_bf16(a0, b, part[0][nf], 0, 0, 0);
                part[1][nf] = __builtin_amdgcn_mfma_f32_16x16x32_bf16(a1, b, part[1][nf], 0, 0, 0);
            }
        }
        if (t & 1) {
            int kb = t >> 1;
            float sw = swp[kb];
            #pragma unroll
            for (int fm = 0; fm < 2; ++fm) {
                float c0 = xs_l[m * 32 + fm * 16 + l4 * 4 + 0][kb] * sw;
                float c1 = xs_l[m * 32 + fm * 16 + l4 * 4 + 1][kb] * sw;
                float c2 = xs_l[m * 32 + fm * 16 + l4 * 4 + 2][kb] * sw;
                float c3 = xs_l[m * 32 + fm * 16 + l4 * 4 + 3][kb] * sw;
                #pragma unroll
                for (int nf = 0; nf < 4; ++nf) {
                    master[fm][nf][0] += c0 * part[fm][nf][0];
                    master[fm][nf][1] += c1 * part[fm][nf][1];
                    master[fm][nf][2] += c2 * part[fm][nf][2];
                    master[fm][nf][3] += c3 * part[fm][nf][3];
                    part[fm][nf] = (f4v){0,0,0,0};
                }
            }
        }
        __syncthreads();
    }

    // epilogue: q=1 waves park up in LDS; q=0 waves fuse silu(gate)*up -> hbuf f32
    float* Ul = (float*)sm;   // [64][65]
    if (q == 1) {
        #pragma unroll
        for (int fm = 0; fm < 2; ++fm)
            #pragma unroll
            for (int nf = 0; nf < 4; ++nf)
                #pragma unroll
                for (int r = 0; r < 4; ++r)
                    Ul[(m * 32 + fm * 16 + l4 * 4 + r) * 65 + nf * 16 + l15] = master[fm][nf][r];
    }
    __syncthreads();
    if (q == 0) {
        #pragma unroll
        for (int fm = 0; fm < 2; ++fm)
            #pragma unroll
            for (int r = 0; r < 4; ++r) {
                int row = m * 32 + fm * 16 + l4 * 4 + r;
                int p = ptok[row];
                if (p < 0) continue;
                float* drow = hbuf + (size_t)p * I_DIM + it * 64;
                #pragma unroll
                for (int nf = 0; nf < 4; ++nf) {
                    float g = master[fm][nf][r];
                    float u = Ul[row * 65 + nf * 16 + l15];
                    drow[nf * 16 + l15] = (g / (1.0f + expf(-g))) * u;
                }
            }
    }
}

// ---------- K4: h -> fp8 codes (bf16) + per-128-group scales ----------
__global__ void k_quant_h(const float* __restrict__ h, u16* __restrict__ hq,
                          float* __restrict__ hs) {
    int p = blockIdx.x, tid = threadIdx.x;   // 128 threads, 4 f32 each
    float4 v = ((const float4*)(h + (size_t)p * I_DIM))[tid];
    float a = fmaxf(fmaxf(fabsf(v.x), fabsf(v.y)), fmaxf(fabsf(v.z), fabsf(v.w)));
    #pragma unroll
    for (int m = 16; m >= 1; m >>= 1) a = fmaxf(a, __shfl_xor(a, m));
    float s = fmaxf(a, 1e-10f) / 448.0f;
    ushort4 r;
    r.x = (u16)f2bf(fp8_rt(fminf(fmaxf(v.x / s, -448.f), 448.f)));
    r.y = (u16)f2bf(fp8_rt(fminf(fmaxf(v.y / s, -448.f), 448.f)));
    r.z = (u16)f2bf(fp8_rt(fminf(fmaxf(v.z / s, -448.f), 448.f)));
    r.w = (u16)f2bf(fp8_rt(fminf(fmaxf(v.w / s, -448.f), 448.f)));
    ((ushort4*)(hq + (size_t)p * I_DIM))[tid] = r;
    if ((tid & 31) == 0) hs[p * 4 + (tid >> 5)] = s;
}

// ---------- K5: down MFMA GEMM (R3-proven) + rw-weighted partial write ----------
// grid 2048: e = bid&15, tile = bid>>4: tt = tile>>3, nt = tile&7 (128 H-cols).
// K=512, BK=64 (8 chunks), fold every 2 (kb = t>>1, 4 scale blocks).
__global__ __launch_bounds__(256, 3)
void k_down(const u16* __restrict__ hq, const float* __restrict__ hs,
            const int* __restrict__ counts, const int* __restrict__ lists,
            const u16* __restrict__ wdn, const float* __restrict__ sdn,
            const float* __restrict__ tkw, const u16* __restrict__ zbuf,
            float* __restrict__ dout) {
    int bid = blockIdx.x;
    int e = bid & 15, tile = bid >> 4;
    int tt = tile >> 3, nt = tile & 7;
    int n = counts[e];
    if (tt * 64 >= n) return;

    __shared__ __align__(16) u16 sm[2][12288];
    __shared__ float hs_l[64][4];
    __shared__ float rw_l[64];
    __shared__ int ptok[64];

    int tid = threadIdx.x;
    int w = tid >> 6, lane = tid & 63;
    int m = w & 1, q = w >> 1;
    int l15 = lane & 15, l4 = lane >> 4;

    if (tid < 64) {
        int slot = tt * 64 + tid;
        ptok[tid] = (slot < n) ? lists[e * NPAIR + slot] : -1;
    }
    __syncthreads();
    {
        int r = tid >> 2, kb = tid & 3;
        int p = ptok[r];
        hs_l[r][kb] = (p >= 0) ? hs[p * 4 + kb] : 0.f;
        if (tid < 64) rw_l[tid] = (ptok[tid] >= 0) ? tkw[ptok[tid]] : 0.f;
    }

    const u16* wbase = wdn + (size_t)e * H_DIM * I_DIM;
    const u16* srcB[4];
    #pragma unroll
    for (int j = 0; j < 4; ++j) {
        int s = j * 256 + tid;
        int row = s >> 3, c = s & 7, cg = c ^ (row & 7);
        srcB[j] = wbase + (size_t)(nt * 128 + row) * I_DIM + cg * 8;
    }
    const u16* srcA[2];
    #pragma unroll
    for (int j = 0; j < 2; ++j) {
        int s = j * 256 + tid;
        int row = s >> 3, c = s & 7, cg = c ^ (row & 7);
        int p = ptok[row];
        srcA[j] = (p >= 0) ? hq + (size_t)p * I_DIM + cg * 8 : zbuf;
    }

    int idxA[2][2], idxB[4][2];
    #pragma unroll
    for (int fm = 0; fm < 2; ++fm) {
        int ar = m * 32 + fm * 16 + l15;
        #pragma unroll
        for (int kg = 0; kg < 2; ++kg)
            idxA[fm][kg] = 8192 + ar * 64 + (((kg * 4 + l4) ^ (ar & 7)) * 8);
    }
    #pragma unroll
    for (int nf = 0; nf < 4; ++nf) {
        int br = q * 64 + nf * 16 + l15;
        #pragma unroll
        for (int kg = 0; kg < 2; ++kg)
            idxB[nf][kg] = br * 64 + (((kg * 4 + l4) ^ (br & 7)) * 8);
    }

    auto stage = [&](int buf) {
        #pragma unroll
        for (int j = 0; j < 4; ++j) { GLDS(srcB[j], &sm[buf][j * 2048 + tid * 8]); srcB[j] += 64; }
        #pragma unroll
        for (int j = 0; j < 2; ++j) { GLDS(srcA[j], &sm[buf][8192 + j * 2048 + tid * 8]); srcA[j] += 64; }
    };

    f4v master[2][4], part[2][4];
    #pragma unroll
    for (int a = 0; a < 2; ++a)
        #pragma unroll
        for (int b = 0; b < 4; ++b) { master[a][b] = (f4v){0,0,0,0}; part[a][b] = (f4v){0,0,0,0}; }

    const float* swp = sdn + (e * 8 + nt) * 4;

    stage(0);
    __syncthreads();

    for (int t = 0; t < 8; ++t) {
        if (t < 7) stage((t + 1) & 1);
        const u16* buf = &sm[t & 1][0];
        #pragma unroll
        for (int kg = 0; kg < 2; ++kg) {
            s8v a0 = *(const s8v*)&buf[idxA[0][kg]];
            s8v a1 = *(const s8v*)&buf[idxA[1][kg]];
            #pragma unroll
            for (int nf = 0; nf < 4; ++nf) {
                s8v b = *(const s8v*)&buf[idxB[nf][kg]];
                part[0][nf] = __builtin_amdgcn_mfma_f32_16x16x32_bf16(a0, b, part[0][nf], 0, 0, 0);
                part[1][nf] = __builtin_amdgcn_mfma_f32_16x16x32_bf16(a1, b, part[1][nf], 0, 0, 0);
            }
        }
        if (t & 1) {
            int kb = t >> 1;
            float sw = swp[kb];
            #pragma unroll
            for (int fm = 0; fm < 2; ++fm) {
                float c0 = hs_l[m * 32 + fm * 16 + l4 * 4 + 0][kb] * sw;
                float c1 = hs_l[m * 32 + fm * 16 + l4 * 4 + 1][kb] * sw;
                float c2 = hs_l[m * 32 + fm * 16 + l4 * 4 + 2][kb] * sw;
                float c3 = hs_l[m * 32 + fm * 16 + l4 * 4 + 3][kb] * sw;
                #pragma unroll
                for (int nf = 0; nf < 4; ++nf) {
                    master[fm][nf][0] += c0 * part[fm][nf][0];
                    master[fm][nf][1] += c1 * part[fm][nf][1];
                    master[fm][nf][2] += c2 * part[fm][nf][2];
                    master[fm][nf][3] += c3 * part[fm][nf][3];
                    part[fm][nf] = (f4v){0,0,0,0};
                }
            }
        }
        __syncthreads();
    }

    #pragma unroll
    for (int fm = 0; fm < 2; ++fm)
        #pragma unroll
        for (int r = 0; r < 4; ++r) {
            int row = m * 32 + fm * 16 + l4 * 4 + r;
            int p = ptok[row];
            if (p < 0) continue;
            float rw = rw_l[row];
            float* drow = dout + (size_t)p * H_DIM + nt * 128 + q * 64;
            #pragma unroll
            for (int nf = 0; nf < 4; ++nf)
                drow[nf * 16 + l15] = rw * master[fm][nf][r];
        }
}

// ---------- K6: sum the 4 slot-partials per token ----------
__global__ void k_reduce(const float* __restrict__ dout, float* __restrict__ out) {
    int i = blockIdx.x * 256 + threadIdx.x;   // f32x4 index over T*H
    int t = i >> 8, h4 = i & 255;
    const float4* d = (const float4*)dout;
    float4 a = d[(size_t)(t * 4 + 0) * 256 + h4];
    float4 b = d[(size_t)(t * 4 + 1) * 256 + h4];
    float4 c = d[(size_t)(t * 4 + 2) * 256 + h4];
    float4 e = d[(size_t)(t * 4 + 3) * 256 + h4];
    float4 r;
    r.x = a.x + b.x + c.x + e.x;
    r.y = a.y + b.y + c.y + e.y;
    r.z = a.z + b.z + c.z + e.z;
    r.w = a.w + b.w + c.w + e.w;
    ((float4*)out)[i] = r;
}

extern "C" void kernel_launch(void* const* d_in, const int* in_sizes, int n_in,
                              void* d_out, int out_size, void* d_ws, size_t ws_size,
                              hipStream_t stream) {
    const float* hs_in = (const float*)d_in[0];
    const int*   tki = (const int*)d_in[1];
    const float* tkw = (const float*)d_in[2];
    const float* wgu = (const float*)d_in[3];
    const float* sgu = (const float*)d_in[4];
    const float* wdn = (const float*)d_in[5];
    const float* sdn = (const float*)d_in[6];
    float* out = (float*)d_out;

    char* ws = (char*)d_ws;
    const size_t MB = 1024 * 1024;
    u16*   wgu_bf = (u16*)(ws);                    // 32 MB; ALIASED by dout after k_gateup
    float* dout   = (float*)(ws);                  // 32 MB (NPAIR*H f32)
    u16*   wdn_bf = (u16*)(ws + 32 * MB);          // 16 MB
    u16*   xq     = (u16*)(ws + 48 * MB);          // 4 MB
    float* xs     = (float*)(ws + 52 * MB);        // 64 KB
    float* hbuf   = (float*)(ws + 53 * MB);        // 16 MB (NPAIR*I f32)
    u16*   hq     = (u16*)(ws + 69 * MB);          // 8 MB
    float* hs     = (float*)(ws + 77 * MB);        // 128 KB
    int*   counts = (int*)(ws + 78 * MB);          // 64 ints (zeroed below)
    u16*   zbuf   = (u16*)(ws + 78 * MB + 4096);   // 4 KB zeros (zeroed below)
    int*   lists  = (int*)(ws + 78 * MB + 65536);  // 512 KB

    // single memset covers counts (4 KB region) + zbuf (4 KB)
    hipMemsetAsync(ws + 78 * MB, 0, 8192, stream);

    k_prep<<<26624, 256, 0, stream>>>(wgu, wgu_bf, wdn, wdn_bf, hs_in, xq, xs,
                                      tki, counts, lists);
    k_gateup<<<2048, 256, 0, stream>>>(xq, xs, counts, lists, wgu_bf, sgu, zbuf, hbuf);
    k_quant_h<<<NPAIR, 128, 0, stream>>>(hbuf, hq, hs);
    k_down<<<2048, 256, 0, stream>>>(hq, hs, counts, lists, wdn_bf, sdn, tkw, zbuf, dout);
    k_reduce<<<T_TOK * H_DIM / 1024, 256, 0, stream>>>(dout, out);
}

// Round 10
// 214.090 us; speedup vs baseline: 1.1658x; 1.1658x over previous
//
#include <hip/hip_runtime.h>
#include <math.h>

#define T_TOK 2048
#define H_DIM 1024
#define I_DIM 512
#define N_EXP 16
#define TOPK  4
#define NPAIR (T_TOK*TOPK)   /* 8192 */

typedef unsigned short u16;
typedef unsigned char u8;
typedef __attribute__((ext_vector_type(4))) float f4v;   // MFMA accumulator

#define GLDS(g, l) __builtin_amdgcn_global_load_lds( \
    (const __attribute__((address_space(1))) void*)(g), \
    (__attribute__((address_space(3))) void*)(l), 16, 0, 0)

// ---------- fp8 e4m3fn round-trip (RNE); input must be in [-448,448] ----------
__device__ __forceinline__ float fp8_rt(float v) {
    float av = fabsf(v);
    if (av < 0.015625f) {                 // subnormal region: quantum 2^-9
        return rintf(v * 512.0f) * 0.001953125f;
    }
    unsigned u = __float_as_uint(v);
    unsigned lsb = (u >> 20) & 1u;        // keep 3 mantissa bits, RNE
    u = (u + 0x7FFFFu + lsb) & 0xFFF00000u;
    return __uint_as_float(u);
}

// ---------- exact f32 -> fp8 e4m3fn code (input must be exactly representable) ----------
__device__ __forceinline__ unsigned f2fp8(float v) {
    unsigned u = __float_as_uint(v);
    unsigned s = (u >> 24) & 0x80u;       // sign -> bit 7
    float av = fabsf(v);
    if (av < 0.015625f) return s | (unsigned)(av * 512.0f);   // subnormal: exact int 0..7
    unsigned e = ((u >> 23) & 0xFFu) - 120u;                  // e4m3 exponent field 1..15
    return s | (e << 3) | ((u >> 20) & 7u);
}

// ---------- K0: routing via single-block LDS histogram (no global atomics) ----------
__global__ void k_route2(const int* __restrict__ tki, int* __restrict__ counts,
                         int* __restrict__ lists) {
    __shared__ int cnt[16];
    int tid = threadIdx.x;                // 1024 threads, 8 pairs each
    if (tid < 16) cnt[tid] = 0;
    __syncthreads();
    #pragma unroll
    for (int j = 0; j < 8; ++j) {
        int p = tid * 8 + j;
        int e = tki[p];
        int pos = atomicAdd(&cnt[e], 1);  // LDS atomic: cheap
        lists[e * NPAIR + pos] = p;
    }
    __syncthreads();
    if (tid < 16) counts[tid] = cnt[tid];
}

// ---------- K1: prep = weight cvt (f32 -> fp8 codes) + x quant ----------
// blocks [0, 24576): cvt. blocks [24576, 26624): token t = bid-24576: quant x row.
#define NF4_GU (N_EXP * 2 * I_DIM * H_DIM / 4)   /* 4194304 float4 slots */
__global__ void k_prep(const float* __restrict__ wgu, u8* __restrict__ wgu_f8,
                       const float* __restrict__ wdn, u8* __restrict__ wdn_f8,
                       const float* __restrict__ x, u8* __restrict__ xq,
                       float* __restrict__ xs) {
    int bid = blockIdx.x, tid = threadIdx.x;
    if (bid < 24576) {
        int i = bid * 256 + tid;                 // float4 slot
        const float* in = wgu; u8* out = wgu_f8;
        if (i >= NF4_GU) { in = wdn; out = wdn_f8; i -= NF4_GU; }
        float4 a = ((const float4*)in)[i];
        unsigned pk = f2fp8(a.x) | (f2fp8(a.y) << 8) | (f2fp8(a.z) << 16) | (f2fp8(a.w) << 24);
        ((unsigned*)out)[i] = pk;
    } else {
        int t = bid - 24576;
        float4 v = ((const float4*)(x + (size_t)t * H_DIM))[tid];
        float a = fmaxf(fmaxf(fabsf(v.x), fabsf(v.y)), fmaxf(fabsf(v.z), fabsf(v.w)));
        #pragma unroll
        for (int m = 16; m >= 1; m >>= 1) a = fmaxf(a, __shfl_xor(a, m));
        float s = fmaxf(a, 1e-10f) / 448.0f;
        unsigned pk = f2fp8(fp8_rt(fminf(fmaxf(v.x / s, -448.f), 448.f)))
                    | (f2fp8(fp8_rt(fminf(fmaxf(v.y / s, -448.f), 448.f))) << 8)
                    | (f2fp8(fp8_rt(fminf(fmaxf(v.z / s, -448.f), 448.f))) << 16)
                    | (f2fp8(fp8_rt(fminf(fmaxf(v.w / s, -448.f), 448.f))) << 24);
        ((unsigned*)(xq + (size_t)t * H_DIM))[tid] = pk;
        if ((tid & 31) == 0) xs[t * 8 + (tid >> 5)] = s;
    }
}

// ---------- K3: gate_up fp8 MFMA GEMM (R3 skeleton, BK=128 fp8, 8 chunks) ----------
// grid 2048: e = bid&15 (XCD pin), tile = bid>>4: tt = tile>>3 (64-pair M-tile),
// it = tile&7 (64 gate cols + 64 up cols). 4 waves: m = w&1, q = w>>1 (gate|up).
// Per buf: B [128 rows][128 B] + A [64][128 B] = 24 KB. 16B-granule XOR swizzle (row&7).
__global__ __launch_bounds__(256, 3)
void k_gateup(const u8* __restrict__ xq, const float* __restrict__ xs,
              const int* __restrict__ counts, const int* __restrict__ lists,
              const u8* __restrict__ wgu, const float* __restrict__ sgu,
              const u8* __restrict__ zbuf, float* __restrict__ hbuf) {
    int bid = blockIdx.x;
    int e = bid & 15, tile = bid >> 4;
    int tt = tile >> 3, it = tile & 7;
    int n = counts[e];
    if (tt * 64 >= n) return;

    __shared__ __align__(16) u8 sm[2][24576];
    __shared__ float xs_l[64][8];
    __shared__ int ptok[64];

    int tid = threadIdx.x;
    int w = tid >> 6, lane = tid & 63;
    int m = w & 1, q = w >> 1;
    int l15 = lane & 15, l4 = lane >> 4;

    if (tid < 64) {
        int slot = tt * 64 + tid;
        ptok[tid] = (slot < n) ? lists[e * NPAIR + slot] : -1;
    }
    __syncthreads();
    {
        int r = tid >> 2, kb4 = (tid & 3) * 2;
        int p = ptok[r];
        xs_l[r][kb4]     = (p >= 0) ? xs[(p >> 2) * 8 + kb4]     : 0.f;
        xs_l[r][kb4 + 1] = (p >= 0) ? xs[(p >> 2) * 8 + kb4 + 1] : 0.f;
    }

    // staging sources: pre-swizzled 16B granules (c8 ^ (row&7)); LDS dest linear
    const u8* wbase = wgu + (size_t)e * (2 * I_DIM) * H_DIM;
    const u8* srcB[4];
    #pragma unroll
    for (int j = 0; j < 4; ++j) {
        int s = j * 256 + tid;
        int row = s >> 3, c8 = s & 7, cg = c8 ^ (row & 7);
        int nrow = (row < 64) ? it * 64 + row : 448 + it * 64 + row;  // gate | up
        srcB[j] = wbase + (size_t)nrow * H_DIM + cg * 16;
    }
    const u8* srcA[2];
    #pragma unroll
    for (int j = 0; j < 2; ++j) {
        int s = j * 256 + tid;
        int row = s >> 3, c8 = s & 7, cg = c8 ^ (row & 7);
        int p = ptok[row];
        srcA[j] = (p >= 0) ? xq + (size_t)(p >> 2) * H_DIM + cg * 16 : zbuf;
    }

    // fragment LDS byte offsets: row*128 + ((u>>1)^(row&7))*16 + (u&1)*8, u = kg*4+l4
    int idxA[2][4], idxB[4][4];
    #pragma unroll
    for (int fm = 0; fm < 2; ++fm) {
        int ar = m * 32 + fm * 16 + l15;
        #pragma unroll
        for (int kg = 0; kg < 4; ++kg) {
            int u = kg * 4 + l4;
            idxA[fm][kg] = 16384 + ar * 128 + (((u >> 1) ^ (ar & 7)) << 4) + ((u & 1) << 3);
        }
    }
    #pragma unroll
    for (int nf = 0; nf < 4; ++nf) {
        int br = q * 64 + nf * 16 + l15;
        #pragma unroll
        for (int kg = 0; kg < 4; ++kg) {
            int u = kg * 4 + l4;
            idxB[nf][kg] = br * 128 + (((u >> 1) ^ (br & 7)) << 4) + ((u & 1) << 3);
        }
    }

    auto stage = [&](int buf) {
        #pragma unroll
        for (int j = 0; j < 4; ++j) { GLDS(srcB[j], &sm[buf][(j * 256 + tid) * 16]); srcB[j] += 128; }
        #pragma unroll
        for (int j = 0; j < 2; ++j) { GLDS(srcA[j], &sm[buf][16384 + (j * 256 + tid) * 16]); srcA[j] += 128; }
    };

    f4v master[2][4], part[2][4];
    #pragma unroll
    for (int a = 0; a < 2; ++a)
        #pragma unroll
        for (int b = 0; b < 4; ++b) { master[a][b] = (f4v){0,0,0,0}; part[a][b] = (f4v){0,0,0,0}; }

    const float* swp = sgu + e * 64 + (q ? 4 + (it >> 1) : (it >> 1)) * 8;

    stage(0);
    __syncthreads();

    for (int t = 0; t < 8; ++t) {
        if (t < 7) stage((t + 1) & 1);
        const u8* buf = &sm[t & 1][0];
        #pragma unroll
        for (int kg = 0; kg < 4; ++kg) {
            long a0 = *(const long*)&buf[idxA[0][kg]];
            long a1 = *(const long*)&buf[idxA[1][kg]];
            #pragma unroll
            for (int nf = 0; nf < 4; ++nf) {
                long b = *(const long*)&buf[idxB[nf][kg]];
                part[0][nf] = __builtin_amdgcn_mfma_f32_16x16x32_fp8_fp8(a0, b, part[0][nf], 0, 0, 0);
                part[1][nf] = __builtin_amdgcn_mfma_f32_16x16x32_fp8_fp8(a1, b, part[1][nf], 0, 0, 0);
            }
        }
        {   // fold: one K-block (128) per chunk
            float sw = swp[t];
            #pragma unroll
            for (int fm = 0; fm < 2; ++fm) {
                float c0 = xs_l[m * 32 + fm * 16 + l4 * 4 + 0][t] * sw;
                float c1 = xs_l[m * 32 + fm * 16 + l4 * 4 + 1][t] * sw;
                float c2 = xs_l[m * 32 + fm * 16 + l4 * 4 + 2][t] * sw;
                float c3 = xs_l[m * 32 + fm * 16 + l4 * 4 + 3][t] * sw;
                #pragma unroll
                for (int nf = 0; nf < 4; ++nf) {
                    master[fm][nf][0] += c0 * part[fm][nf][0];
                    master[fm][nf][1] += c1 * part[fm][nf][1];
                    master[fm][nf][2] += c2 * part[fm][nf][2];
                    master[fm][nf][3] += c3 * part[fm][nf][3];
                    part[fm][nf] = (f4v){0,0,0,0};
                }
            }
        }
        __syncthreads();
    }

    // epilogue: q=1 waves park up in LDS; q=0 waves fuse silu(gate)*up -> hbuf f32
    float* Ul = (float*)sm;   // [64][65]
    if (q == 1) {
        #pragma unroll
        for (int fm = 0; fm < 2; ++fm)
            #pragma unroll
            for (int nf = 0; nf < 4; ++nf)
                #pragma unroll
                for (int r = 0; r < 4; ++r)
                    Ul[(m * 32 + fm * 16 + l4 * 4 + r) * 65 + nf * 16 + l15] = master[fm][nf][r];
    }
    __syncthreads();
    if (q == 0) {
        #pragma unroll
        for (int fm = 0; fm < 2; ++fm)
            #pragma unroll
            for (int r = 0; r < 4; ++r) {
                int row = m * 32 + fm * 16 + l4 * 4 + r;
                int p = ptok[row];
                if (p < 0) continue;
                float* drow = hbuf + (size_t)p * I_DIM + it * 64;
                #pragma unroll
                for (int nf = 0; nf < 4; ++nf) {
                    float g = master[fm][nf][r];
                    float u = Ul[row * 65 + nf * 16 + l15];
                    drow[nf * 16 + l15] = (g / (1.0f + expf(-g))) * u;
                }
            }
    }
}

// ---------- K4: h -> fp8 codes + per-128-group scales ----------
__global__ void k_quant_h(const float* __restrict__ h, u8* __restrict__ hq,
                          float* __restrict__ hs) {
    int p = blockIdx.x, tid = threadIdx.x;   // 128 threads, 4 f32 each
    float4 v = ((const float4*)(h + (size_t)p * I_DIM))[tid];
    float a = fmaxf(fmaxf(fabsf(v.x), fabsf(v.y)), fmaxf(fabsf(v.z), fabsf(v.w)));
    #pragma unroll
    for (int m = 16; m >= 1; m >>= 1) a = fmaxf(a, __shfl_xor(a, m));
    float s = fmaxf(a, 1e-10f) / 448.0f;
    unsigned pk = f2fp8(fp8_rt(fminf(fmaxf(v.x / s, -448.f), 448.f)))
                | (f2fp8(fp8_rt(fminf(fmaxf(v.y / s, -448.f), 448.f))) << 8)
                | (f2fp8(fp8_rt(fminf(fmaxf(v.z / s, -448.f), 448.f))) << 16)
                | (f2fp8(fp8_rt(fminf(fmaxf(v.w / s, -448.f), 448.f))) << 24);
    ((unsigned*)(hq + (size_t)p * I_DIM))[tid] = pk;
    if ((tid & 31) == 0) hs[p * 4 + (tid >> 5)] = s;
}

// ---------- K5: down fp8 MFMA GEMM (BK=128, 4 chunks) + rw-weighted partial write ----------
__global__ __launch_bounds__(256, 3)
void k_down(const u8* __restrict__ hq, const float* __restrict__ hs,
            const int* __restrict__ counts, const int* __restrict__ lists,
            const u8* __restrict__ wdn, const float* __restrict__ sdn,
            const float* __restrict__ tkw, const u8* __restrict__ zbuf,
            float* __restrict__ dout) {
    int bid = blockIdx.x;
    int e = bid & 15, tile = bid >> 4;
    int tt = tile >> 3, nt = tile & 7;
    int n = counts[e];
    if (tt * 64 >= n) return;

    __shared__ __align__(16) u8 sm[2][24576];
    __shared__ float hs_l[64][4];
    __shared__ float rw_l[64];
    __shared__ int ptok[64];

    int tid = threadIdx.x;
    int w = tid >> 6, lane = tid & 63;
    int m = w & 1, q = w >> 1;
    int l15 = lane & 15, l4 = lane >> 4;

    if (tid < 64) {
        int slot = tt * 64 + tid;
        ptok[tid] = (slot < n) ? lists[e * NPAIR + slot] : -1;
    }
    __syncthreads();
    {
        int r = tid >> 2, kb = tid & 3;
        int p = ptok[r];
        hs_l[r][kb] = (p >= 0) ? hs[p * 4 + kb] : 0.f;
        if (tid < 64) rw_l[tid] = (ptok[tid] >= 0) ? tkw[ptok[tid]] : 0.f;
    }

    const u8* wbase = wdn + (size_t)e * H_DIM * I_DIM;
    const u8* srcB[4];
    #pragma unroll
    for (int j = 0; j < 4; ++j) {
        int s = j * 256 + tid;
        int row = s >> 3, c8 = s & 7, cg = c8 ^ (row & 7);
        srcB[j] = wbase + (size_t)(nt * 128 + row) * I_DIM + cg * 16;
    }
    const u8* srcA[2];
    #pragma unroll
    for (int j = 0; j < 2; ++j) {
        int s = j * 256 + tid;
        int row = s >> 3, c8 = s & 7, cg = c8 ^ (row & 7);
        int p = ptok[row];
        srcA[j] = (p >= 0) ? hq + (size_t)p * I_DIM + cg * 16 : zbuf;
    }

    int idxA[2][4], idxB[4][4];
    #pragma unroll
    for (int fm = 0; fm < 2; ++fm) {
        int ar = m * 32 + fm * 16 + l15;
        #pragma unroll
        for (int kg = 0; kg < 4; ++kg) {
            int u = kg * 4 + l4;
            idxA[fm][kg] = 16384 + ar * 128 + (((u >> 1) ^ (ar & 7)) << 4) + ((u & 1) << 3);
        }
    }
    #pragma unroll
    for (int nf = 0; nf < 4; ++nf) {
        int br = q * 64 + nf * 16 + l15;
        #pragma unroll
        for (int kg = 0; kg < 4; ++kg) {
            int u = kg * 4 + l4;
            idxB[nf][kg] = br * 128 + (((u >> 1) ^ (br & 7)) << 4) + ((u & 1) << 3);
        }
    }

    auto stage = [&](int buf) {
        #pragma unroll
        for (int j = 0; j < 4; ++j) { GLDS(srcB[j], &sm[buf][(j * 256 + tid) * 16]); srcB[j] += 128; }
        #pragma unroll
        for (int j = 0; j < 2; ++j) { GLDS(srcA[j], &sm[buf][16384 + (j * 256 + tid) * 16]); srcA[j] += 128; }
    };

    f4v master[2][4], part[2][4];
    #pragma unroll
    for (int a = 0; a < 2; ++a)
        #pragma unroll
        for (int b = 0; b < 4; ++b) { master[a][b] = (f4v){0,0,0,0}; part[a][b] = (f4v){0,0,0,0}; }

    const float* swp = sdn + (e * 8 + nt) * 4;

    stage(0);
    __syncthreads();

    for (int t = 0; t < 4; ++t) {
        if (t < 3) stage((t + 1) & 1);
        const u8* buf = &sm[t & 1][0];
        #pragma unroll
        for (int kg = 0; kg < 4; ++kg) {
            long a0 = *(const long*)&buf[idxA[0][kg]];
            long a1 = *(const long*)&buf[idxA[1][kg]];
            #pragma unroll
            for (int nf = 0; nf < 4; ++nf) {
                long b = *(const long*)&buf[idxB[nf][kg]];
                part[0][nf] = __builtin_amdgcn_mfma_f32_16x16x32_fp8_fp8(a0, b, part[0][nf], 0, 0, 0);
                part[1][nf] = __builtin_amdgcn_mfma_f32_16x16x32_fp8_fp8(a1, b, part[1][nf], 0, 0, 0);
            }
        }
        {
            float sw = swp[t];
            #pragma unroll
            for (int fm = 0; fm < 2; ++fm) {
                float c0 = hs_l[m * 32 + fm * 16 + l4 * 4 + 0][t] * sw;
                float c1 = hs_l[m * 32 + fm * 16 + l4 * 4 + 1][t] * sw;
                float c2 = hs_l[m * 32 + fm * 16 + l4 * 4 + 2][t] * sw;
                float c3 = hs_l[m * 32 + fm * 16 + l4 * 4 + 3][t] * sw;
                #pragma unroll
                for (int nf = 0; nf < 4; ++nf) {
                    master[fm][nf][0] += c0 * part[fm][nf][0];
                    master[fm][nf][1] += c1 * part[fm][nf][1];
                    master[fm][nf][2] += c2 * part[fm][nf][2];
                    master[fm][nf][3] += c3 * part[fm][nf][3];
                    part[fm][nf] = (f4v){0,0,0,0};
                }
            }
        }
        __syncthreads();
    }

    #pragma unroll
    for (int fm = 0; fm < 2; ++fm)
        #pragma unroll
        for (int r = 0; r < 4; ++r) {
            int row = m * 32 + fm * 16 + l4 * 4 + r;
            int p = ptok[row];
            if (p < 0) continue;
            float rw = rw_l[row];
            float* drow = dout + (size_t)p * H_DIM + nt * 128 + q * 64;
            #pragma unroll
            for (int nf = 0; nf < 4; ++nf)
                drow[nf * 16 + l15] = rw * master[fm][nf][r];
        }
}

// ---------- K6: sum the 4 slot-partials per token ----------
__global__ void k_reduce(const float* __restrict__ dout, float* __restrict__ out) {
    int i = blockIdx.x * 256 + threadIdx.x;   // f32x4 index over T*H
    int t = i >> 8, h4 = i & 255;
    const float4* d = (const float4*)dout;
    float4 a = d[(size_t)(t * 4 + 0) * 256 + h4];
    float4 b = d[(size_t)(t * 4 + 1) * 256 + h4];
    float4 c = d[(size_t)(t * 4 + 2) * 256 + h4];
    float4 e = d[(size_t)(t * 4 + 3) * 256 + h4];
    float4 r;
    r.x = a.x + b.x + c.x + e.x;
    r.y = a.y + b.y + c.y + e.y;
    r.z = a.z + b.z + c.z + e.z;
    r.w = a.w + b.w + c.w + e.w;
    ((float4*)out)[i] = r;
}

extern "C" void kernel_launch(void* const* d_in, const int* in_sizes, int n_in,
                              void* d_out, int out_size, void* d_ws, size_t ws_size,
                              hipStream_t stream) {
    const float* hs_in = (const float*)d_in[0];
    const int*   tki = (const int*)d_in[1];
    const float* tkw = (const float*)d_in[2];
    const float* wgu = (const float*)d_in[3];
    const float* sgu = (const float*)d_in[4];
    const float* wdn = (const float*)d_in[5];
    const float* sdn = (const float*)d_in[6];
    float* out = (float*)d_out;

    char* ws = (char*)d_ws;
    const size_t MB = 1024 * 1024;
    u8*    wgu_f8 = (u8*)(ws);                     // 16 MB; ALIASED by dout after k_gateup
    float* dout   = (float*)(ws);                  // 32 MB (NPAIR*H f32)
    u8*    wdn_f8 = (u8*)(ws + 32 * MB);           // 8 MB
    u8*    xq     = (u8*)(ws + 40 * MB);           // 2 MB
    float* xs     = (float*)(ws + 42 * MB);        // 64 KB
    float* hbuf   = (float*)(ws + 43 * MB);        // 16 MB (NPAIR*I f32)
    u8*    hq     = (u8*)(ws + 59 * MB);           // 4 MB
    float* hs     = (float*)(ws + 63 * MB);        // 128 KB
    int*   counts = (int*)(ws + 64 * MB);          // 64 ints (zeroed below)
    u8*    zbuf   = (u8*)(ws + 64 * MB + 4096);    // 4 KB zeros (zeroed below)
    int*   lists  = (int*)(ws + 64 * MB + 65536);  // 512 KB

    hipMemsetAsync(ws + 64 * MB, 0, 8192, stream);

    k_route2<<<1, 1024, 0, stream>>>(tki, counts, lists);
    k_prep<<<26624, 256, 0, stream>>>(wgu, wgu_f8, wdn, wdn_f8, hs_in, xq, xs);
    k_gateup<<<2048, 256, 0, stream>>>(xq, xs, counts, lists, wgu_f8, sgu, zbuf, hbuf);
    k_quant_h<<<NPAIR, 128, 0, stream>>>(hbuf, hq, hs);
    k_down<<<2048, 256, 0, stream>>>(hq, hs, counts, lists, wdn_f8, sdn, tkw, zbuf, dout);
    k_reduce<<<T_TOK * H_DIM / 1024, 256, 0, stream>>>(dout, out);
}